// Round 6
// baseline (118.572 us; speedup 1.0000x reference)
//
#include <hip/hip_runtime.h>

typedef __attribute__((ext_vector_type(8))) short short8_t;      // 8 bf16
typedef __attribute__((ext_vector_type(4))) float float4_t;      // MFMA C/D frag

#define MFMA __builtin_amdgcn_mfma_f32_16x16x32_bf16

constexpr int BB   = 4;
constexpr int LL   = 2048;
constexpr int DM   = 1024;
constexpr int DK   = 128;
constexpr int MTOT = BB * LL;     // 8192
constexpr int MC   = 8;           // m-chunks in attention kernel
constexpr float INV2PI = 0.15915494309189535f;

// Fragment-major image layout (all ws tensors): a lane's MFMA fragment is one
// contiguous 16B chunk; a wave's fragment read is one coalesced 1KB global
// load (dwordx4 per lane). No LDS staging anywhere; L1/L2/L3 serve reuse.

__device__ __forceinline__ unsigned short f2bf(float f) {
    unsigned int u = __builtin_bit_cast(unsigned int, f);
    u += 0x7FFFu + ((u >> 16) & 1u);          // RNE
    return (unsigned short)(u >> 16);
}
__device__ __forceinline__ float bf2f(unsigned short h) {
    unsigned int u = ((unsigned int)h) << 16;
    return __builtin_bit_cast(float, u);
}

// ---------------------------------------------------------------------------
// K0: W [1024 k][128 n] f32 -> fragment-major W^T images, hi/lo bf16.
// Image: [kc 32][cbt 8][g 4][cc 16][e 8]; element (n,k): kc=k>>5, g=(k>>3)&3,
// e=k&7, cbt=n>>4, cc=n&15.  grid (32 kc, 3 arr), block 256.
// ---------------------------------------------------------------------------
__global__ __launch_bounds__(256) void k0_wsplit(
        const float* __restrict__ wq, const float* __restrict__ wk,
        const float* __restrict__ wv,
        unsigned short* __restrict__ wqh, unsigned short* __restrict__ wql,
        unsigned short* __restrict__ wkh, unsigned short* __restrict__ wkl,
        unsigned short* __restrict__ wvh) {
    int kc = blockIdx.x, a = blockIdx.y;
    const float* w = (a == 0) ? wq : (a == 1) ? wk : wv;
    __shared__ float tile[32 * 132];          // [k 32][n 128] pad->132
    int t = threadIdx.x;
#pragma unroll
    for (int j = 0; j < 4; ++j) {
        int idx4 = t + j * 256;               // 1024 float4s
        int kr = idx4 >> 5, n4 = idx4 & 31;
        *(float4_t*)(&tile[kr * 132 + n4 * 4]) =
            *(const float4_t*)(w + (size_t)(kc * 32 + kr) * DK + n4 * 4);
    }
    __syncthreads();
#pragma unroll
    for (int sw = 0; sw < 2; ++sw) {
        int ch = t + sw * 256;                // 512 16B-chunks: (cbt*4+g)*16+cc
        int cbt = ch >> 6, g = (ch >> 4) & 3, cc = ch & 15;
        short8_t hh, ll;
#pragma unroll
        for (int e = 0; e < 8; ++e) {
            float f = tile[(g * 8 + e) * 132 + cbt * 16 + cc];
            unsigned short h = f2bf(f);
            hh[e] = (short)h;
            ll[e] = (short)f2bf(f - bf2f(h));
        }
        size_t off = (size_t)kc * 4096 + ch * 8;
        if (a == 0) { *(short8_t*)(wqh + off) = hh; *(short8_t*)(wql + off) = ll; }
        else if (a == 1) { *(short8_t*)(wkh + off) = hh; *(short8_t*)(wkl + off) = ll; }
        else { *(short8_t*)(wvh + off) = hh; }
    }
}

// ---------------------------------------------------------------------------
// K1 v4: QKV projection. BM=32, BK=32; grid (256 mt, 3 grp), 4 waves, wave
// tile 32r x 32c (rf=2, cf=2). NO LDS, NO BARRIERS: A read direct from x
// (reg-pipelined 2-deep), B read direct from fragment-major W images (L2).
// ---------------------------------------------------------------------------
__global__ __launch_bounds__(256) void k1_proj(
        const float* __restrict__ x,
        const float* __restrict__ bq, const float* __restrict__ bk,
        const float* __restrict__ bv,
        const unsigned short* __restrict__ wqh, const unsigned short* __restrict__ wql,
        const unsigned short* __restrict__ wkh, const unsigned short* __restrict__ wkl,
        const unsigned short* __restrict__ wvh,
        unsigned short* __restrict__ qih, unsigned short* __restrict__ qil,
        unsigned short* __restrict__ kih, unsigned short* __restrict__ kil,
        unsigned short* __restrict__ vit) {
    int mt = blockIdx.x, grp = blockIdx.y;
    int rowbase = mt * 32;
    int t = threadIdx.x, lane = t & 63, wid = t >> 6;
    int cc = lane & 15, g = lane >> 4;
    const bool split = (grp < 2);
    const unsigned short* Wh = (grp == 0) ? wqh : (grp == 1) ? wkh : wvh;
    const unsigned short* Wl = (grp == 0) ? wql : wkl;

    const float* xr0 = x + (size_t)(rowbase + cc) * DM + g * 8;       // rf=0
    const float* xr1 = x + (size_t)(rowbase + 16 + cc) * DM + g * 8;  // rf=1

    float4_t acc[2][2];
#pragma unroll
    for (int rf = 0; rf < 2; ++rf)
#pragma unroll
        for (int cf = 0; cf < 2; ++cf) acc[rf][cf] = (float4_t){0.f, 0.f, 0.f, 0.f};

    // named-register double pipeline (rule #20: static indexing only)
    float4_t aE[2][2], aO[2][2];
    short8_t bhE[2], blE[2], bhO[2], blO[2];

    auto loadA = [&](int kc, float4_t (&A)[2][2]) {
        A[0][0] = *(const float4_t*)(xr0 + kc * 32);
        A[0][1] = *(const float4_t*)(xr0 + kc * 32 + 4);
        A[1][0] = *(const float4_t*)(xr1 + kc * 32);
        A[1][1] = *(const float4_t*)(xr1 + kc * 32 + 4);
    };
    auto loadB = [&](int kc, short8_t (&Bh)[2], short8_t (&Bl)[2]) {
#pragma unroll
        for (int cf = 0; cf < 2; ++cf) {
            size_t o = (size_t)kc * 4096 + (wid * 2 + cf) * 512 + g * 128 + cc * 8;
            Bh[cf] = *(const short8_t*)(Wh + o);
            if (split) Bl[cf] = *(const short8_t*)(Wl + o);
        }
    };
    auto comp = [&](float4_t (&A)[2][2], short8_t (&Bh)[2], short8_t (&Bl)[2]) {
        short8_t ah[2], al[2];
#pragma unroll
        for (int rf = 0; rf < 2; ++rf)
#pragma unroll
            for (int e = 0; e < 8; ++e) {
                float f = A[rf][e >> 2][e & 3];
                unsigned short h = f2bf(f);
                ah[rf][e] = (short)h;
                if (split) al[rf][e] = (short)f2bf(f - bf2f(h));
            }
#pragma unroll
        for (int cf = 0; cf < 2; ++cf)
#pragma unroll
            for (int rf = 0; rf < 2; ++rf) {
                acc[rf][cf] = MFMA(ah[rf], Bh[cf], acc[rf][cf], 0, 0, 0);
                if (split) {
                    acc[rf][cf] = MFMA(ah[rf], Bl[cf], acc[rf][cf], 0, 0, 0);
                    acc[rf][cf] = MFMA(al[rf], Bh[cf], acc[rf][cf], 0, 0, 0);
                }
            }
    };

    loadA(0, aE); loadB(0, bhE, blE);
#pragma unroll 1
    for (int kc = 0; kc < 32; kc += 2) {
        loadA(kc + 1, aO); loadB(kc + 1, bhO, blO);   // prefetch odd
        comp(aE, bhE, blE);
        if (kc + 2 < 32) { loadA(kc + 2, aE); loadB(kc + 2, bhE, blE); }
        comp(aO, bhO, blO);
    }

    // ---- epilogue: bias, split-cast, scatter into fragment-major images
    const float* bias = (grp == 0) ? bq : (grp == 1) ? bk : bv;
#pragma unroll
    for (int rf = 0; rf < 2; ++rf)
#pragma unroll
        for (int cf = 0; cf < 2; ++cf) {
            int c = wid * 32 + cf * 16 + cc;
            float bv_ = bias[c];
#pragma unroll
            for (int i = 0; i < 4; ++i) {
                int r = rowbase + rf * 16 + g * 4 + i;
                float v = acc[rf][cf][i] + bv_;
                unsigned short h = f2bf(v);
                if (grp == 0) {
                    size_t o = (size_t)(r >> 4) * 2048 + (c >> 5) * 512 +
                               ((c >> 3) & 3) * 128 + (r & 15) * 8 + (c & 7);
                    qih[o] = h; qil[o] = f2bf(v - bf2f(h));
                } else if (grp == 1) {
                    size_t o = (size_t)(r >> 5) * 4096 + ((r >> 4) & 1) * 2048 +
                               (c >> 5) * 512 + ((c >> 3) & 3) * 128 +
                               (r & 15) * 8 + (c & 7);
                    kih[o] = h; kil[o] = f2bf(v - bf2f(h));
                } else {
                    size_t o = (size_t)(r >> 5) * 4096 + (c >> 4) * 512 +
                               ((r >> 3) & 3) * 128 + (c & 15) * 8 + (r & 7);
                    vit[o] = h;
                }
            }
        }
}

// ---------------------------------------------------------------------------
// K2 v3: out_partial = cos(Q K^T) V. grid (MC=8, L/64, B); 4 waves, 16 q-rows
// each; 8 KV-tiles of 32 per block. NO K/V LDS, NO BARRIERS: fragments read
// direct from images (identical across waves -> L1 broadcast). P per-wave LDS.
// ---------------------------------------------------------------------------
__global__ __launch_bounds__(256) void k2_attn(
        const unsigned short* __restrict__ qih, const unsigned short* __restrict__ qil,
        const unsigned short* __restrict__ kih, const unsigned short* __restrict__ kil,
        const unsigned short* __restrict__ vit, float* __restrict__ part) {
    int mc = blockIdx.x, qt = blockIdx.y, b = blockIdx.z;
    int t = threadIdx.x, lane = t & 63, wid = t >> 6;
    int cc = lane & 15, g = lane >> 4;

    __shared__ __attribute__((aligned(16))) unsigned short ps[4][512];   // per-wave P

    int qrow = b * LL + qt * 64 + wid * 16;
    size_t qb = (size_t)(qrow >> 4) * 2048;
    short8_t qhf[4], qlf[4];
#pragma unroll
    for (int s = 0; s < 4; ++s) {
        size_t off = qb + s * 512 + g * 128 + cc * 8;
        qhf[s] = *(const short8_t*)(qih + off);
        qlf[s] = *(const short8_t*)(qil + off);
    }
    float4_t o[8];
#pragma unroll
    for (int cf = 0; cf < 8; ++cf) o[cf] = (float4_t){0.f, 0.f, 0.f, 0.f};

    int tbase = b * 64 + mc * 8;   // 32-row tile index base

#pragma unroll 1
    for (int mi = 0; mi < 8; ++mi) {
        const unsigned short* kt = kih + (size_t)(tbase + mi) * 4096;
        const unsigned short* lt = kil + (size_t)(tbase + mi) * 4096;
        const unsigned short* vt = vit + (size_t)(tbase + mi) * 4096;
        // ---- S = Q K^T (3-term split), S-tile 16q x 32m
        float4_t sa[2];
#pragma unroll
        for (int cf = 0; cf < 2; ++cf) sa[cf] = (float4_t){0.f, 0.f, 0.f, 0.f};
#pragma unroll
        for (int cf = 0; cf < 2; ++cf)
#pragma unroll
            for (int s = 0; s < 4; ++s) {
                int off = cf * 2048 + s * 512 + g * 128 + cc * 8;
                short8_t bh = *(const short8_t*)(kt + off);
                short8_t bl = *(const short8_t*)(lt + off);
                sa[cf] = MFMA(qhf[s], bh, sa[cf], 0, 0, 0);
                sa[cf] = MFMA(qhf[s], bl, sa[cf], 0, 0, 0);
                sa[cf] = MFMA(qlf[s], bh, sa[cf], 0, 0, 0);
            }
        // ---- P = cos(S) -> per-wave fragment-major LDS [m>>3][q][m&7]
#pragma unroll
        for (int cf = 0; cf < 2; ++cf)
#pragma unroll
            for (int i = 0; i < 4; ++i) {
                float rv = sa[cf][i] * INV2PI;
                rv = rv - floorf(rv);
                float cv;
                asm volatile("v_cos_f32 %0, %1" : "=v"(cv) : "v"(rv));
                int m = cf * 16 + cc, q = g * 4 + i;
                ps[wid][(m >> 3) * 128 + q * 8 + (m & 7)] = f2bf(cv);
            }
        // ---- out += P @ V  (same-wave LDS write->read; lgkmcnt only)
        short8_t pa = *(const short8_t*)(&ps[wid][g * 128 + cc * 8]);
#pragma unroll
        for (int cf = 0; cf < 8; ++cf) {
            short8_t vb = *(const short8_t*)(vt + cf * 512 + g * 128 + cc * 8);
            o[cf] = MFMA(pa, vb, o[cf], 0, 0, 0);
        }
    }
    float* pp = part + ((size_t)(mc * BB + b) * LL + qt * 64 + wid * 16) * DK;
#pragma unroll
    for (int cf = 0; cf < 8; ++cf)
#pragma unroll
        for (int i = 0; i < 4; ++i)
            pp[(g * 4 + i) * DK + cf * 16 + cc] = o[cf][i];
}

// ---------------------------------------------------------------------------
// K3: out = sum of MC partials
// ---------------------------------------------------------------------------
__global__ __launch_bounds__(256) void k3_reduce(const float4_t* __restrict__ part,
                                                 float4_t* __restrict__ out) {
    constexpr int NT4 = MTOT * DK / 4;
    int idx = blockIdx.x * 256 + threadIdx.x;
    float4_t s = part[idx];
#pragma unroll
    for (int c = 1; c < MC; ++c) s += part[idx + (size_t)c * NT4];
    out[idx] = s;
}

// ---------------------------------------------------------------------------
extern "C" void kernel_launch(void* const* d_in, const int* in_sizes, int n_in,
                              void* d_out, int out_size, void* d_ws, size_t ws_size,
                              hipStream_t stream) {
    const float* x  = (const float*)d_in[0];
    const float* Wq = (const float*)d_in[1];
    const float* bq = (const float*)d_in[2];
    const float* Wk = (const float*)d_in[3];
    const float* bk = (const float*)d_in[4];
    const float* Wv = (const float*)d_in[5];
    const float* bv = (const float*)d_in[6];

    char* ws = (char*)d_ws;
    size_t off = 0;
    auto alloc = [&](size_t bytes) -> char* {
        char* p = ws + off;
        off += (bytes + 255) & ~(size_t)255;
        return p;
    };
    unsigned short* wqh = (unsigned short*)alloc((size_t)DK * DM * 2);
    unsigned short* wql = (unsigned short*)alloc((size_t)DK * DM * 2);
    unsigned short* wkh = (unsigned short*)alloc((size_t)DK * DM * 2);
    unsigned short* wkl = (unsigned short*)alloc((size_t)DK * DM * 2);
    unsigned short* wvh = (unsigned short*)alloc((size_t)DK * DM * 2);
    unsigned short* qih = (unsigned short*)alloc((size_t)MTOT * DK * 2);
    unsigned short* qil = (unsigned short*)alloc((size_t)MTOT * DK * 2);
    unsigned short* kih = (unsigned short*)alloc((size_t)MTOT * DK * 2);
    unsigned short* kil = (unsigned short*)alloc((size_t)MTOT * DK * 2);
    unsigned short* vit = (unsigned short*)alloc((size_t)MTOT * DK * 2);
    float* part = (float*)alloc((size_t)MC * MTOT * DK * 4);

    k0_wsplit<<<dim3(32, 3), 256, 0, stream>>>(Wq, Wk, Wv, wqh, wql, wkh, wkl, wvh);
    k1_proj<<<dim3(MTOT / 32, 3), 256, 0, stream>>>(x, bq, bk, bv,
                                                    wqh, wql, wkh, wkl, wvh,
                                                    qih, qil, kih, kil, vit);
    k2_attn<<<dim3(MC, LL / 64, BB), 256, 0, stream>>>(qih, qil, kih, kil, vit, part);
    k3_reduce<<<(MTOT * DK / 4) / 256, 256, 0, stream>>>((const float4_t*)part,
                                                         (float4_t*)d_out);
}

// Round 7
// 72.065 us; speedup vs baseline: 1.6453x; 1.6453x over previous
//
#include <hip/hip_runtime.h>

typedef __attribute__((ext_vector_type(8))) short short8_t;      // 8 bf16
typedef __attribute__((ext_vector_type(4))) short short4_t;      // 4 bf16
typedef __attribute__((ext_vector_type(4))) float float4_t;      // MFMA C/D frag

#define MFMA __builtin_amdgcn_mfma_f32_16x16x32_bf16
#define VMCNT(n) asm volatile("s_waitcnt vmcnt(" #n ")" ::: "memory")
#define LGKM0    asm volatile("s_waitcnt lgkmcnt(0)" ::: "memory")
#define BARRIER  __builtin_amdgcn_s_barrier()

constexpr int BB   = 4;
constexpr int LL   = 2048;
constexpr int DM   = 1024;
constexpr int DK   = 128;
constexpr int MTOT = BB * LL;     // 8192
constexpr int MC   = 4;
constexpr float INV2PI = 0.15915494309189535f;

// Fragment-major image layout (all ws tensors): a lane's MFMA fragment is one
// contiguous 16B chunk; gload_lds staging is linear (rule #21 satisfied by
// pre-permuted global images).

__device__ __forceinline__ unsigned short f2bf(float f) {
    unsigned int u = __builtin_bit_cast(unsigned int, f);
    u += 0x7FFFu + ((u >> 16) & 1u);          // RNE
    return (unsigned short)(u >> 16);
}
__device__ __forceinline__ float bf2f(unsigned short h) {
    unsigned int u = ((unsigned int)h) << 16;
    return __builtin_bit_cast(float, u);
}
__device__ __forceinline__ void gload16(const void* g, void* l) {
    __builtin_amdgcn_global_load_lds(
        (const __attribute__((address_space(1))) void*)g,
        (__attribute__((address_space(3))) void*)l, 16, 0, 0);
}

// ---------------------------------------------------------------------------
// K0: W [1024 k][128 n] f32 -> fragment-major W^T images, hi/lo bf16.
// Image: [kc 32][cbt 8][g 4][cc 16][e 8]; element (n,k): kc=k>>5, g=(k>>3)&3,
// e=k&7, cbt=n>>4, cc=n&15.  grid (32 kc, 3 arr), block 256.
// ---------------------------------------------------------------------------
__global__ __launch_bounds__(256) void k0_wsplit(
        const float* __restrict__ wq, const float* __restrict__ wk,
        const float* __restrict__ wv,
        unsigned short* __restrict__ wqh, unsigned short* __restrict__ wql,
        unsigned short* __restrict__ wkh, unsigned short* __restrict__ wkl,
        unsigned short* __restrict__ wvh) {
    int kc = blockIdx.x, a = blockIdx.y;
    const float* w = (a == 0) ? wq : (a == 1) ? wk : wv;
    __shared__ float tile[32 * 132];          // [k 32][n 128] pad->132
    int t = threadIdx.x;
#pragma unroll
    for (int j = 0; j < 4; ++j) {
        int idx4 = t + j * 256;               // 1024 float4s
        int kr = idx4 >> 5, n4 = idx4 & 31;
        *(float4_t*)(&tile[kr * 132 + n4 * 4]) =
            *(const float4_t*)(w + (size_t)(kc * 32 + kr) * DK + n4 * 4);
    }
    __syncthreads();
#pragma unroll
    for (int sw = 0; sw < 2; ++sw) {
        int ch = t + sw * 256;                // 512 16B-chunks: (cbt*4+g)*16+cc
        int cbt = ch >> 6, g = (ch >> 4) & 3, cc = ch & 15;
        short8_t hh, ll;
#pragma unroll
        for (int e = 0; e < 8; ++e) {
            float f = tile[(g * 8 + e) * 132 + cbt * 16 + cc];
            unsigned short h = f2bf(f);
            hh[e] = (short)h;
            ll[e] = (short)f2bf(f - bf2f(h));
        }
        size_t off = (size_t)kc * 4096 + ch * 8;
        if (a == 0) { *(short8_t*)(wqh + off) = hh; *(short8_t*)(wql + off) = ll; }
        else if (a == 1) { *(short8_t*)(wkh + off) = hh; *(short8_t*)(wkl + off) = ll; }
        else { *(short8_t*)(wvh + off) = hh; }
    }
}

// ---------------------------------------------------------------------------
// K1 v5: QKV projection. BM=32, BK=32; grid (256 mt, 3 grp), 4 waves, wave
// tile 32r x 32c. Counted-vmcnt 2-phase: STAGE(k+1) -> vmcnt(N) -> barrier ->
// compute(k) -> lgkm0 -> barrier. Prefetch stays in flight across barriers.
// ---------------------------------------------------------------------------
__global__ __launch_bounds__(256, 3) void k1_proj(
        const float* __restrict__ x,
        const float* __restrict__ bq, const float* __restrict__ bk,
        const float* __restrict__ bv,
        const unsigned short* __restrict__ wqh, const unsigned short* __restrict__ wql,
        const unsigned short* __restrict__ wkh, const unsigned short* __restrict__ wkl,
        const unsigned short* __restrict__ wvh,
        unsigned short* __restrict__ qih, unsigned short* __restrict__ qil,
        unsigned short* __restrict__ kih, unsigned short* __restrict__ kil,
        unsigned short* __restrict__ vit) {
    int mt = blockIdx.x, grp = blockIdx.y;
    int rowbase = mt * 32;
    __shared__ __attribute__((aligned(16))) unsigned short wbh[2][4096]; // 8KB/buf
    __shared__ __attribute__((aligned(16))) unsigned short wbl[2][4096];
    __shared__ __attribute__((aligned(16))) unsigned short xbh[2][1024]; // 2KB/buf
    __shared__ __attribute__((aligned(16))) unsigned short xbl[2][1024];

    int t = threadIdx.x, lane = t & 63, wid = t >> 6;
    int cc = lane & 15, g = lane >> 4;
    const bool split = (grp < 2);
    const unsigned short* Wh = (grp == 0) ? wqh : (grp == 1) ? wkh : wvh;
    const unsigned short* Wl = (grp == 0) ? wql : wkl;

    float4_t acc[2][2];
#pragma unroll
    for (int rf = 0; rf < 2; ++rf)
#pragma unroll
        for (int cf = 0; cf < 2; ++cf) acc[rf][cf] = (float4_t){0.f, 0.f, 0.f, 0.f};

    // x staging: thread t handles half-chunk: chunk = t>>1 (linear 16B chunks
    // -> ds_write_b64 at byte t*8: conflict-free). chunk = rf*64 + g*16 + cc.
    int xch = t >> 1, xh_ = t & 1;
    int xrf = xch >> 6, xg = (xch >> 4) & 3, xcc = xch & 15;
    const float* xsrc = x + (size_t)(rowbase + xrf * 16 + xcc) * DM + xg * 8 + xh_ * 4;
    int xoff = xch * 8 + xh_ * 4;             // shorts

    // ---- prologue: stage kc=0
    {
        float4_t xf = *(const float4_t*)(xsrc);
        __builtin_amdgcn_sched_barrier(0);
        gload16(Wh + t * 8, (char*)wbh[0] + wid * 1024);
        gload16(Wh + 2048 + t * 8, (char*)wbh[0] + 4096 + wid * 1024);
        if (split) {
            gload16(Wl + t * 8, (char*)wbl[0] + wid * 1024);
            gload16(Wl + 2048 + t * 8, (char*)wbl[0] + 4096 + wid * 1024);
        }
        short4_t hh, ll;
#pragma unroll
        for (int e = 0; e < 4; ++e) {
            unsigned short h = f2bf(xf[e]);
            hh[e] = (short)h;
            ll[e] = (short)f2bf(xf[e] - bf2f(h));
        }
        *(short4_t*)(xbh[0] + xoff) = hh;
        if (split) *(short4_t*)(xbl[0] + xoff) = ll;
        LGKM0;
    }

#pragma unroll 1
    for (int kc = 0; kc < 32; ++kc) {
        int cb = kc & 1, nb = cb ^ 1;
        bool more = (kc < 31);
        float4_t xf;
        if (more) {
            xf = *(const float4_t*)(xsrc + (kc + 1) * 32);
            __builtin_amdgcn_sched_barrier(0);       // keep x-load before gloads
            const unsigned short* Whn = Wh + (size_t)(kc + 1) * 4096;
            gload16(Whn + t * 8, (char*)wbh[nb] + wid * 1024);
            gload16(Whn + 2048 + t * 8, (char*)wbh[nb] + 4096 + wid * 1024);
            if (split) {
                const unsigned short* Wln = Wl + (size_t)(kc + 1) * 4096;
                gload16(Wln + t * 8, (char*)wbl[nb] + wid * 1024);
                gload16(Wln + 2048 + t * 8, (char*)wbl[nb] + 4096 + wid * 1024);
                VMCNT(5);     // newer in flight: x(1) + g(4); g(k) retired
            } else {
                VMCNT(3);     // newer: x(1) + g(2)
            }
        } else {
            VMCNT(0);
        }
        BARRIER;
        // ---- compute on cur buffer (fragment reads: 16B at lane*8 shorts)
        short8_t ah[2], al[2], bh2[2], bl2[2];
        ah[0] = *(const short8_t*)(xbh[cb] + lane * 8);
        ah[1] = *(const short8_t*)(xbh[cb] + 512 + lane * 8);
        if (split) {
            al[0] = *(const short8_t*)(xbl[cb] + lane * 8);
            al[1] = *(const short8_t*)(xbl[cb] + 512 + lane * 8);
        }
#pragma unroll
        for (int cf = 0; cf < 2; ++cf) {
            bh2[cf] = *(const short8_t*)(wbh[cb] + (wid * 2 + cf) * 512 + lane * 8);
            if (split)
                bl2[cf] = *(const short8_t*)(wbl[cb] + (wid * 2 + cf) * 512 + lane * 8);
        }
#pragma unroll
        for (int cf = 0; cf < 2; ++cf)
#pragma unroll
            for (int rf = 0; rf < 2; ++rf) {
                acc[rf][cf] = MFMA(ah[rf], bh2[cf], acc[rf][cf], 0, 0, 0);
                if (split) {
                    acc[rf][cf] = MFMA(ah[rf], bl2[cf], acc[rf][cf], 0, 0, 0);
                    acc[rf][cf] = MFMA(al[rf], bh2[cf], acc[rf][cf], 0, 0, 0);
                }
            }
        // ---- convert next-x late, write to nb
        if (more) {
            short4_t hh, ll;
#pragma unroll
            for (int e = 0; e < 4; ++e) {
                unsigned short h = f2bf(xf[e]);
                hh[e] = (short)h;
                ll[e] = (short)f2bf(xf[e] - bf2f(h));
            }
            *(short4_t*)(xbh[nb] + xoff) = hh;
            if (split) *(short4_t*)(xbl[nb] + xoff) = ll;
        }
        LGKM0;
        BARRIER;
    }

    // ---- epilogue: bias, split-cast, scatter into fragment-major images
    const float* bias = (grp == 0) ? bq : (grp == 1) ? bk : bv;
#pragma unroll
    for (int rf = 0; rf < 2; ++rf)
#pragma unroll
        for (int cf = 0; cf < 2; ++cf) {
            int c = wid * 32 + cf * 16 + cc;
            float bv_ = bias[c];
#pragma unroll
            for (int i = 0; i < 4; ++i) {
                int r = rowbase + rf * 16 + g * 4 + i;
                float v = acc[rf][cf][i] + bv_;
                unsigned short h = f2bf(v);
                if (grp == 0) {
                    size_t o = (size_t)(r >> 4) * 2048 + (c >> 5) * 512 +
                               ((c >> 3) & 3) * 128 + (r & 15) * 8 + (c & 7);
                    qih[o] = h; qil[o] = f2bf(v - bf2f(h));
                } else if (grp == 1) {
                    size_t o = (size_t)(r >> 5) * 4096 + ((r >> 4) & 1) * 2048 +
                               (c >> 5) * 512 + ((c >> 3) & 3) * 128 +
                               (r & 15) * 8 + (c & 7);
                    kih[o] = h; kil[o] = f2bf(v - bf2f(h));
                } else {
                    size_t o = (size_t)(r >> 5) * 4096 + (c >> 4) * 512 +
                               ((r >> 3) & 3) * 128 + (c & 15) * 8 + (r & 7);
                    vit[o] = h;
                }
            }
        }
}

// ---------------------------------------------------------------------------
// K2 v4: out_partial = cos(Q K^T) V. grid (MC=4, L/64, B); 4 waves, 16 q-rows
// each; KVBLK=32, 16 steps. Counted-vmcnt 2-phase double buffer.
// ---------------------------------------------------------------------------
__global__ __launch_bounds__(256, 2) void k2_attn(
        const unsigned short* __restrict__ qih, const unsigned short* __restrict__ qil,
        const unsigned short* __restrict__ kih, const unsigned short* __restrict__ kil,
        const unsigned short* __restrict__ vit, float* __restrict__ part) {
    int mc = blockIdx.x, qt = blockIdx.y, b = blockIdx.z;
    int t = threadIdx.x, lane = t & 63, wid = t >> 6;
    int cc = lane & 15, g = lane >> 4;

    __shared__ __attribute__((aligned(16))) unsigned short kbh[2][4096]; // 8KB/buf
    __shared__ __attribute__((aligned(16))) unsigned short kbl[2][4096];
    __shared__ __attribute__((aligned(16))) unsigned short vbt[2][4096];
    __shared__ __attribute__((aligned(16))) unsigned short ps[4][512];   // per-wave P

    int qrow = b * LL + qt * 64 + wid * 16;
    size_t qb = (size_t)(qrow >> 4) * 2048;
    short8_t qhf[4], qlf[4];
#pragma unroll
    for (int s = 0; s < 4; ++s) {
        size_t off = qb + s * 512 + g * 128 + cc * 8;
        qhf[s] = *(const short8_t*)(qih + off);
        qlf[s] = *(const short8_t*)(qil + off);
    }
    float4_t o[8];
#pragma unroll
    for (int cf = 0; cf < 8; ++cf) o[cf] = (float4_t){0.f, 0.f, 0.f, 0.f};

    int tbase = b * 64 + mc * 16;   // 32-row tile index base

    // ---- prologue: stage mi=0 -> buf0 (6 gloads, stay in flight)
    {
        const unsigned short* ks = kih + (size_t)tbase * 4096;
        const unsigned short* ls = kil + (size_t)tbase * 4096;
        const unsigned short* vs = vit + (size_t)tbase * 4096;
        gload16(ks + t * 8, (char*)kbh[0] + wid * 1024);
        gload16(ks + 2048 + t * 8, (char*)kbh[0] + 4096 + wid * 1024);
        gload16(ls + t * 8, (char*)kbl[0] + wid * 1024);
        gload16(ls + 2048 + t * 8, (char*)kbl[0] + 4096 + wid * 1024);
        gload16(vs + t * 8, (char*)vbt[0] + wid * 1024);
        gload16(vs + 2048 + t * 8, (char*)vbt[0] + 4096 + wid * 1024);
    }

#pragma unroll 1
    for (int mi = 0; mi < 16; ++mi) {
        int cb = mi & 1, nb = cb ^ 1;
        if (mi < 15) {
            const unsigned short* ks = kih + (size_t)(tbase + mi + 1) * 4096;
            const unsigned short* ls = kil + (size_t)(tbase + mi + 1) * 4096;
            const unsigned short* vs = vit + (size_t)(tbase + mi + 1) * 4096;
            gload16(ks + t * 8, (char*)kbh[nb] + wid * 1024);
            gload16(ks + 2048 + t * 8, (char*)kbh[nb] + 4096 + wid * 1024);
            gload16(ls + t * 8, (char*)kbl[nb] + wid * 1024);
            gload16(ls + 2048 + t * 8, (char*)kbl[nb] + 4096 + wid * 1024);
            gload16(vs + t * 8, (char*)vbt[nb] + wid * 1024);
            gload16(vs + 2048 + t * 8, (char*)vbt[nb] + 4096 + wid * 1024);
            VMCNT(6);     // newer in flight: 6 gloads(k+1); g(k) retired
        } else {
            VMCNT(0);
        }
        BARRIER;
        // ---- S = Q K^T (3-term split), S-tile 16q x 32m
        float4_t sa[2];
#pragma unroll
        for (int cf = 0; cf < 2; ++cf) sa[cf] = (float4_t){0.f, 0.f, 0.f, 0.f};
#pragma unroll
        for (int cf = 0; cf < 2; ++cf)
#pragma unroll
            for (int s = 0; s < 4; ++s) {
                int off = cf * 2048 + s * 512 + g * 128 + cc * 8;
                short8_t bh = *(const short8_t*)(kbh[cb] + off);
                short8_t bl = *(const short8_t*)(kbl[cb] + off);
                sa[cf] = MFMA(qhf[s], bh, sa[cf], 0, 0, 0);
                sa[cf] = MFMA(qhf[s], bl, sa[cf], 0, 0, 0);
                sa[cf] = MFMA(qlf[s], bh, sa[cf], 0, 0, 0);
            }
        // ---- P = cos(S) -> per-wave fragment-major LDS [m>>3][q][m&7]
#pragma unroll
        for (int cf = 0; cf < 2; ++cf)
#pragma unroll
            for (int i = 0; i < 4; ++i) {
                float rv = sa[cf][i] * INV2PI;
                rv = rv - floorf(rv);
                float cv;
                asm volatile("v_cos_f32 %0, %1" : "=v"(cv) : "v"(rv));
                int m = cf * 16 + cc, q = g * 4 + i;
                ps[wid][(m >> 3) * 128 + q * 8 + (m & 7)] = f2bf(cv);
            }
        // ---- out += P @ V  (same-wave LDS write->read, DS pipe in-order)
        short8_t pa = *(const short8_t*)(&ps[wid][g * 128 + cc * 8]);
#pragma unroll
        for (int cf = 0; cf < 8; ++cf) {
            short8_t vb = *(const short8_t*)(vbt[cb] + cf * 512 + g * 128 + cc * 8);
            o[cf] = MFMA(pa, vb, o[cf], 0, 0, 0);
        }
        LGKM0;
        BARRIER;
    }
    float* pp = part + ((size_t)(mc * BB + b) * LL + qt * 64 + wid * 16) * DK;
#pragma unroll
    for (int cf = 0; cf < 8; ++cf)
#pragma unroll
        for (int i = 0; i < 4; ++i)
            pp[(g * 4 + i) * DK + cf * 16 + cc] = o[cf][i];
}

// ---------------------------------------------------------------------------
// K3: out = sum of MC partials
// ---------------------------------------------------------------------------
__global__ __launch_bounds__(256) void k3_reduce(const float4_t* __restrict__ part,
                                                 float4_t* __restrict__ out) {
    constexpr int NT4 = MTOT * DK / 4;
    int idx = blockIdx.x * 256 + threadIdx.x;
    float4_t s = part[idx];
#pragma unroll
    for (int c = 1; c < MC; ++c) s += part[idx + (size_t)c * NT4];
    out[idx] = s;
}

// ---------------------------------------------------------------------------
extern "C" void kernel_launch(void* const* d_in, const int* in_sizes, int n_in,
                              void* d_out, int out_size, void* d_ws, size_t ws_size,
                              hipStream_t stream) {
    const float* x  = (const float*)d_in[0];
    const float* Wq = (const float*)d_in[1];
    const float* bq = (const float*)d_in[2];
    const float* Wk = (const float*)d_in[3];
    const float* bk = (const float*)d_in[4];
    const float* Wv = (const float*)d_in[5];
    const float* bv = (const float*)d_in[6];

    char* ws = (char*)d_ws;
    size_t off = 0;
    auto alloc = [&](size_t bytes) -> char* {
        char* p = ws + off;
        off += (bytes + 255) & ~(size_t)255;
        return p;
    };
    unsigned short* wqh = (unsigned short*)alloc((size_t)DK * DM * 2);
    unsigned short* wql = (unsigned short*)alloc((size_t)DK * DM * 2);
    unsigned short* wkh = (unsigned short*)alloc((size_t)DK * DM * 2);
    unsigned short* wkl = (unsigned short*)alloc((size_t)DK * DM * 2);
    unsigned short* wvh = (unsigned short*)alloc((size_t)DK * DM * 2);
    unsigned short* qih = (unsigned short*)alloc((size_t)MTOT * DK * 2);
    unsigned short* qil = (unsigned short*)alloc((size_t)MTOT * DK * 2);
    unsigned short* kih = (unsigned short*)alloc((size_t)MTOT * DK * 2);
    unsigned short* kil = (unsigned short*)alloc((size_t)MTOT * DK * 2);
    unsigned short* vit = (unsigned short*)alloc((size_t)MTOT * DK * 2);
    float* part = (float*)alloc((size_t)MC * MTOT * DK * 4);

    k0_wsplit<<<dim3(32, 3), 256, 0, stream>>>(Wq, Wk, Wv, wqh, wql, wkh, wkl, wvh);
    k1_proj<<<dim3(MTOT / 32, 3), 256, 0, stream>>>(x, bq, bk, bv,
                                                    wqh, wql, wkh, wkl, wvh,
                                                    qih, qil, kih, kil, vit);
    k2_attn<<<dim3(MC, LL / 64, BB), 256, 0, stream>>>(qih, qil, kih, kil, vit, part);
    k3_reduce<<<(MTOT * DK / 4) / 256, 256, 0, stream>>>((const float4_t*)part,
                                                         (float4_t*)d_out);
}